// Round 7
// baseline (82.167 us; speedup 1.0000x reference)
//
#include <hip/hip_runtime.h>
#include <cstdint>

#define NB 32
#define NC 512
#define NQ 64
#define ND 512

typedef __attribute__((ext_vector_type(8))) short bf16x8;   // 8 bf16 (4 VGPRs)
typedef __attribute__((ext_vector_type(4))) float f32x4;

__device__ __forceinline__ short f2bf(float f) {   // RNE f32 -> bf16
  union { float f; unsigned u; } v; v.f = f;
  v.u += 0x7fffu + ((v.u >> 16) & 1u);
  return (short)(v.u >> 16);
}

// ============ kPrep: q_bf16 [b][q][d], qT_bf16 [b][d][q], s_q[b][q] (R6, proven) ============
__global__ __launch_bounds__(512) void kPrep(
    const float* __restrict__ qry, const float* __restrict__ W,
    short* __restrict__ qbf, short* __restrict__ qTbf, float* __restrict__ s_q)
{
  __shared__ short lq[NQ*ND];
  const int b = blockIdx.x;
  const int t = threadIdx.x;
  const int r = t >> 3;
  const int cb = (t & 7) * 64;
  const float* qrow = qry + ((size_t)(b*NQ + r))*ND + cb;
  float sq = 0.f;
  #pragma unroll
  for (int i = 0; i < 16; ++i) {
    const float4 qv = *(const float4*)(qrow + i*4);
    const float4 wv = *(const float4*)(W + ND + cb + i*4);
    sq += qv.x*wv.x + qv.y*wv.y + qv.z*wv.z + qv.w*wv.w;
    short4 s; s.x=f2bf(qv.x); s.y=f2bf(qv.y); s.z=f2bf(qv.z); s.w=f2bf(qv.w);
    *(short4*)&qbf[((size_t)(b*NQ + r))*ND + cb + i*4] = s;
    *(short4*)&lq[r*ND + cb + i*4] = s;
  }
  sq += __shfl_xor(sq, 1, 8); sq += __shfl_xor(sq, 2, 8); sq += __shfl_xor(sq, 4, 8);
  if ((t & 7) == 0) s_q[b*NQ + r] = sq;
  __syncthreads();
  const int d = t;
  short* qTrow = qTbf + ((size_t)(b*ND + d))*NQ;
  #pragma unroll
  for (int j = 0; j < 16; ++j) {
    short4 h;
    h.x = lq[(j*4+0)*ND + d];
    h.y = lq[(j*4+1)*ND + d];
    h.z = lq[(j*4+2)*ND + d];
    h.w = lq[(j*4+3)*ND + d];
    *(short4*)&qTrow[j*4] = h;
  }
}

// ============ kS: 2 waves/block, 16 c-rows; GEMM1(q-split) + 2-wave softmax + GEMM2(d-split) ============
// Writes G parts 1,2 + m_ws. All cross-wave LDS exchanges barrier-protected.
__global__ __launch_bounds__(128) void kS(
    const float* __restrict__ ctx, const float* __restrict__ W,
    const short* __restrict__ qbf, const short* __restrict__ qTbf,
    const float* __restrict__ s_q, float* __restrict__ G, float* __restrict__ m_ws)
{
  __shared__ __align__(16) short P[16*72];       // probs bf16 (cols split by wave)
  __shared__ __align__(16) float aqf[2][16*68];  // per-wave aq transpose buffer
  __shared__ float pmL[2][16], peL[2][16];       // partial max / sum per wave
  __shared__ float scf[16];                      // s_c

  const int t    = threadIdx.x;
  const int lane = t & 63;
  const int w    = t >> 6;        // wave 0/1: q-half in GEMM1, d-half in GEMM2
  const int ln15 = lane & 15;
  const int g    = lane >> 4;
  const int bid  = (int)blockIdx.x;
  const int swz  = (bid & 7) * 128 + (bid >> 3);   // XCD-contiguous (1024 % 8 == 0)
  const int b    = swz >> 5;
  const int c0   = (swz & 31) * 16;

  const float* crow = ctx + ((size_t)(b*NC + c0 + ln15))*ND;

  f32x4 acc[2] = {};
  float scp = 0.f;

  // ---- GEMM1: S[16c x 32q(w)] = (ctx*w_m) @ q^T; A in registers, B from global bf16 ----
  #pragma unroll 2
  for (int kc = 0; kc < 8; ++kc) {
    #pragma unroll
    for (int kk = 0; kk < 2; ++kk) {
      const int dd = kc*64 + kk*32 + g*8;
      const float4 c0v = *(const float4*)(crow + dd);
      const float4 c1v = *(const float4*)(crow + dd + 4);
      const float4 wm0 = *(const float4*)(W + 2*ND + dd);
      const float4 wm1 = *(const float4*)(W + 2*ND + dd + 4);
      if (w == 0) {   // s_c only needed once
        const float4 wc0 = *(const float4*)(W + dd);
        const float4 wc1 = *(const float4*)(W + dd + 4);
        scp += c0v.x*wc0.x + c0v.y*wc0.y + c0v.z*wc0.z + c0v.w*wc0.w
             + c1v.x*wc1.x + c1v.y*wc1.y + c1v.z*wc1.z + c1v.w*wc1.w;
      }
      bf16x8 a;
      a[0]=f2bf(c0v.x*wm0.x); a[1]=f2bf(c0v.y*wm0.y); a[2]=f2bf(c0v.z*wm0.z); a[3]=f2bf(c0v.w*wm0.w);
      a[4]=f2bf(c1v.x*wm1.x); a[5]=f2bf(c1v.y*wm1.y); a[6]=f2bf(c1v.z*wm1.z); a[7]=f2bf(c1v.w*wm1.w);
      #pragma unroll
      for (int n = 0; n < 2; ++n) {
        const bf16x8 bq = *(const bf16x8*)&qbf[((size_t)(b*NQ + w*32 + n*16 + ln15))*ND + dd];
        acc[n] = __builtin_amdgcn_mfma_f32_16x16x32_bf16(a, bq, acc[n], 0, 0, 0);
      }
    }
  }

  if (w == 0) {   // s_c for row ln15: reduce over the 4 g-lanes
    scp += __shfl_xor(scp, 16, 64);
    scp += __shfl_xor(scp, 32, 64);
    if (g == 0) scf[ln15] = scp;
  }

  float sqv[2];
  #pragma unroll
  for (int n = 0; n < 2; ++n) sqv[n] = s_q[b*NQ + w*32 + n*16 + ln15];

  // ---- wave-partial softmax over this wave's 32 q ----
  float ev0[4], ev1[4], pmr[4];
  #pragma unroll
  for (int reg = 0; reg < 4; ++reg) {
    float sv0 = acc[0][reg] + sqv[0];
    float sv1 = acc[1][reg] + sqv[1];
    float pm = fmaxf(sv0, sv1);
    pm = fmaxf(pm, __shfl_xor(pm, 1, 16));
    pm = fmaxf(pm, __shfl_xor(pm, 2, 16));
    pm = fmaxf(pm, __shfl_xor(pm, 4, 16));
    pm = fmaxf(pm, __shfl_xor(pm, 8, 16));
    const float e0 = __expf(sv0 - pm), e1 = __expf(sv1 - pm);
    float pe = e0 + e1;
    pe += __shfl_xor(pe, 1, 16); pe += __shfl_xor(pe, 2, 16);
    pe += __shfl_xor(pe, 4, 16); pe += __shfl_xor(pe, 8, 16);
    ev0[reg] = e0; ev1[reg] = e1; pmr[reg] = pm;
    if (ln15 == 0) { pmL[w][g*4 + reg] = pm; peL[w][g*4 + reg] = pe; }
  }
  __syncthreads();   // partials visible

  // ---- combine across the two waves; write normalized P (bf16) ----
  #pragma unroll
  for (int reg = 0; reg < 4; ++reg) {
    const int rloc = g*4 + reg;
    const float m0 = pmL[0][rloc], m1 = pmL[1][rloc];
    const float s0 = peL[0][rloc], s1 = peL[1][rloc];
    const float M  = fmaxf(m0, m1);
    const float S  = s0*__expf(m0 - M) + s1*__expf(m1 - M);
    const float f  = __expf(pmr[reg] - M) / S;
    if (w == 0 && ln15 == 0) m_ws[b*NC + c0 + rloc] = M + scf[rloc];
    P[rloc*72 + w*32 + ln15]      = f2bf(ev0[reg] * f);
    P[rloc*72 + w*32 + 16 + ln15] = f2bf(ev1[reg] * f);
  }
  __syncthreads();   // P complete before fragment loads

  bf16x8 pa[2];
  pa[0] = *(const bf16x8*)&P[ln15*72 + g*8];
  pa[1] = *(const bf16x8*)&P[ln15*72 + 32 + g*8];

  // ---- GEMM2: aq[16c x 256d(w)] = P @ query; fused streaming epilogue (parts 1,2) ----
  for (int dc = 0; dc < 4; ++dc) {
    const int d0 = w*256 + dc*64;
    f32x4 acc2[4] = {};
    #pragma unroll
    for (int kk = 0; kk < 2; ++kk)
      #pragma unroll
      for (int n = 0; n < 4; ++n) {
        const bf16x8 bq = *(const bf16x8*)&qTbf[((size_t)(b*ND + d0 + n*16 + ln15))*NQ + kk*32 + g*8];
        acc2[n] = __builtin_amdgcn_mfma_f32_16x16x32_bf16(pa[kk], bq, acc2[n], 0, 0, 0);
      }
    __syncthreads();   // prior chunk's aqf reads complete (matched across waves)
    #pragma unroll
    for (int n = 0; n < 4; ++n)
      #pragma unroll
      for (int reg = 0; reg < 4; ++reg)
        aqf[w][(g*4 + reg)*68 + n*16 + ln15] = acc2[n][reg];
    __syncthreads();   // aqf visible
    #pragma unroll
    for (int pass = 0; pass < 4; ++pass) {
      const int r = pass*4 + g;
      const float4 aq4 = *(const float4*)&aqf[w][r*68 + ln15*4];
      const float4 cv  = *(const float4*)(ctx + ((size_t)(b*NC + c0 + r))*ND + d0 + ln15*4);
      float* gp = G + ((size_t)(b*NC + c0 + r))*2048 + d0 + ln15*4;
      *(float4*)(gp + 512)  = aq4;                                           // part 1
      *(float4*)(gp + 1024) = make_float4(cv.x*aq4.x, cv.y*aq4.y,
                                          cv.z*aq4.z, cv.w*aq4.w);           // part 2
    }
  }
}

// ============ k2: b = softmax_c(m); attended_context (proven) ============
__global__ __launch_bounds__(256) void k2_partial(
    const float* __restrict__ ctx, const float* __restrict__ m_ws, float* __restrict__ pc)
{
  const int t  = threadIdx.x;
  const int b  = blockIdx.x >> 4;
  const int ch = blockIdx.x & 15;
  __shared__ float r8[8];
  __shared__ float wts[32];

  const float v0 = m_ws[b*NC + t];
  const float v1 = m_ws[b*NC + 256 + t];
  float mx = fmaxf(v0, v1);
  #pragma unroll
  for (int o = 32; o; o >>= 1) mx = fmaxf(mx, __shfl_xor(mx, o, 64));
  if ((t & 63) == 0) r8[t >> 6] = mx;
  __syncthreads();
  mx = fmaxf(fmaxf(r8[0], r8[1]), fmaxf(r8[2], r8[3]));
  float e = __expf(v0 - mx) + __expf(v1 - mx);
  #pragma unroll
  for (int o = 32; o; o >>= 1) e += __shfl_xor(e, o, 64);
  if ((t & 63) == 0) r8[4 + (t >> 6)] = e;
  __syncthreads();
  const float denom = r8[4] + r8[5] + r8[6] + r8[7];
  if (t < 32) wts[t] = __expf(m_ws[b*NC + ch*32 + t] - mx) / denom;
  __syncthreads();

  float s0 = 0.f, s1 = 0.f;
  const float* base = ctx + ((size_t)(b*NC + ch*32))*ND;
  for (int c = 0; c < 32; ++c) {
    const float w = wts[c];
    s0 += w * base[(size_t)c*ND + t];
    s1 += w * base[(size_t)c*ND + t + 256];
  }
  pc[((size_t)(b*16 + ch))*ND + t]       = s0;
  pc[((size_t)(b*16 + ch))*ND + t + 256] = s1;
}

__global__ __launch_bounds__(512) void k2_reduce(
    const float* __restrict__ pc, float* __restrict__ ac)
{
  const int b = blockIdx.x;
  const int d = threadIdx.x;
  float s = 0.f;
  #pragma unroll
  for (int ch = 0; ch < 16; ++ch) s += pc[((size_t)(b*16 + ch))*ND + d];
  ac[b*ND + d] = s;
}

// ============ kFinal: pure streamer, G parts 0 (ctx) and 3 (ctx*ac) ============
__global__ __launch_bounds__(256) void kFinal(
    const float* __restrict__ ctx, const float* __restrict__ ac, float* __restrict__ G)
{
  const size_t e = ((size_t)blockIdx.x*256 + threadIdx.x) * 8;
  const int b = (int)(e >> 18);
  const int r = (int)(e & 262143);
  const int c = r >> 9;
  const int d = r & 511;
  const float4 x0 = *(const float4*)(ctx + e);
  const float4 x1 = *(const float4*)(ctx + e + 4);
  const float4 a0 = *(const float4*)(ac + b*ND + d);
  const float4 a1 = *(const float4*)(ac + b*ND + d + 4);
  float* gp = G + ((size_t)(b*NC + c))*2048 + d;
  *(float4*)(gp)            = x0;                                                      // part 0
  *(float4*)(gp + 4)        = x1;
  *(float4*)(gp + 1536)     = make_float4(x0.x*a0.x, x0.y*a0.y, x0.z*a0.z, x0.w*a0.w); // part 3
  *(float4*)(gp + 1536 + 4) = make_float4(x1.x*a1.x, x1.y*a1.y, x1.z*a1.z, x1.w*a1.w);
}

extern "C" void kernel_launch(void* const* d_in, const int* in_sizes, int n_in,
                              void* d_out, int out_size, void* d_ws, size_t ws_size,
                              hipStream_t stream)
{
  const float* ctx = (const float*)d_in[0];
  const float* qry = (const float*)d_in[1];
  const float* W   = (const float*)d_in[2];
  float* G = (float*)d_out;

  float* ws   = (float*)d_ws;
  float* m_ws = ws;                        // [32][512]
  float* pc   = ws + 16384;                // [32][16][512]
  float* ac   = ws + 278528;               // [32][512]
  float* s_q  = ws + 294912;               // [32][64]
  short* qbf  = (short*)(ws + 296960);     // [32][64][512] bf16
  short* qTbf = qbf + (size_t)NB*NQ*ND;    // [32][512][64] bf16

  kPrep     <<<dim3(NB),    dim3(512), 0, stream>>>(qry, W, qbf, qTbf, s_q);
  kS        <<<dim3(NB*32), dim3(128), 0, stream>>>(ctx, W, qbf, qTbf, s_q, G, m_ws);
  k2_partial<<<dim3(NB*16), dim3(256), 0, stream>>>(ctx, m_ws, pc);
  k2_reduce <<<dim3(NB),    dim3(512), 0, stream>>>(pc, ac);
  kFinal    <<<dim3((NB*NC*ND)/(256*8)), dim3(256), 0, stream>>>(ctx, ac, G);
}

// Round 8
// 65.003 us; speedup vs baseline: 1.2641x; 1.2641x over previous
//
#include <hip/hip_runtime.h>
#include <cstdint>

#define NB 32
#define NC 512
#define NQ 64
#define ND 512

typedef __attribute__((ext_vector_type(8))) short bf16x8;   // 8 bf16 (4 VGPRs)
typedef __attribute__((ext_vector_type(8))) short short8;
typedef __attribute__((ext_vector_type(4))) float f32x4;

__device__ __forceinline__ short f2bf(float f) {   // RNE f32 -> bf16
  union { float f; unsigned u; } v; v.f = f;
  v.u += 0x7fffu + ((v.u >> 16) & 1u);
  return (short)(v.u >> 16);
}

// LDS layout (short units). PITCH=72 shorts (144 B rows; 144=16*9 keeps b128 frags aligned)
#define PITCH 72
#define P_OFF  0       // P bf16 [64 c][72]                  (persists through phase B)
#define CM_OFF 4608    // phase A: ctx*w_m [64][72]; phase B: qT [64 d][72 q]
#define QQ_OFF 9216    // phase A: query [64 q][72]
#define SCS_F  6912    // float idx: s_c[64]
#define SQS_F  6976    // s_q[64]
#define PML_F  7040    // partial max [2][64]
#define PEL_F  7168    // partial sum [2][64]
#define AQF_F  7296    // aq f32 [64][68]
#define AQP    68
#define SM_SHORTS 23296  // 46592 B

__device__ __forceinline__ int qswz(int dd) {  // q-block XOR swizzle for qT row dd
  return (((dd & 7) ^ ((dd >> 3) & 7)) * 8);
}

// ============ k1: GEMM1 + 2-wave softmax + GEMM2; writes G parts 0,1,2 + m_ws ============
// R2 structure at 512 threads (8 waves): wave w -> c-group (w>>1)*16, q/d-half (w&1).
__global__ __launch_bounds__(512) void k1_main(
    const float* __restrict__ ctx, const float* __restrict__ qry,
    const float* __restrict__ W, float* __restrict__ G, float* __restrict__ m_ws)
{
  __shared__ __align__(16) short sm[SM_SHORTS];
  float* smf = (float*)sm;

  const int t    = threadIdx.x;
  const int lane = t & 63;
  const int w    = t >> 6;
  const int ln15 = lane & 15;
  const int g    = lane >> 4;
  const int cw   = (w >> 1) * 16;   // wave's 16 c-rows
  const int qh   = w & 1;           // q-half (GEMM1) / d-half (GEMM2)
  const int qw   = qh * 32;
  const int b    = blockIdx.x >> 3;
  const int c0   = (blockIdx.x & 7) * 64;

  // stagers: 8 threads per row, 8 floats each (256 B contiguous segments)
  const int lr = t >> 3;            // row 0..63
  const int j8 = (t & 7) * 8;

  f32x4 acc[2] = {};
  float scp = 0.f, sqp = 0.f;

  // ---------- Phase A: S = (ctx*w_m) @ query^T, K=512 in 8 chunks ----------
  for (int kc = 0; kc < 8; ++kc) {
    const int d0 = kc * 64;
    __syncthreads();
    {
      const float* crow = ctx + ((size_t)(b*NC + c0 + lr))*ND + d0 + j8;
      const float4 ca = *(const float4*)(crow);
      const float4 cb = *(const float4*)(crow + 4);
      const float4 wca = *(const float4*)(W + d0 + j8);
      const float4 wcb = *(const float4*)(W + d0 + j8 + 4);
      const float4 wma = *(const float4*)(W + 2*ND + d0 + j8);
      const float4 wmb = *(const float4*)(W + 2*ND + d0 + j8 + 4);
      scp += ca.x*wca.x + ca.y*wca.y + ca.z*wca.z + ca.w*wca.w
           + cb.x*wcb.x + cb.y*wcb.y + cb.z*wcb.z + cb.w*wcb.w;
      short8 cs;
      cs[0]=f2bf(ca.x*wma.x); cs[1]=f2bf(ca.y*wma.y); cs[2]=f2bf(ca.z*wma.z); cs[3]=f2bf(ca.w*wma.w);
      cs[4]=f2bf(cb.x*wmb.x); cs[5]=f2bf(cb.y*wmb.y); cs[6]=f2bf(cb.z*wmb.z); cs[7]=f2bf(cb.w*wmb.w);
      *(short8*)&sm[CM_OFF + lr*PITCH + j8] = cs;
    }
    {
      const float* qrow = qry + ((size_t)(b*NQ + lr))*ND + d0 + j8;
      const float4 qa = *(const float4*)(qrow);
      const float4 qb = *(const float4*)(qrow + 4);
      const float4 wqa = *(const float4*)(W + ND + d0 + j8);
      const float4 wqb = *(const float4*)(W + ND + d0 + j8 + 4);
      sqp += qa.x*wqa.x + qa.y*wqa.y + qa.z*wqa.z + qa.w*wqa.w
           + qb.x*wqb.x + qb.y*wqb.y + qb.z*wqb.z + qb.w*wqb.w;
      short8 qs;
      qs[0]=f2bf(qa.x); qs[1]=f2bf(qa.y); qs[2]=f2bf(qa.z); qs[3]=f2bf(qa.w);
      qs[4]=f2bf(qb.x); qs[5]=f2bf(qb.y); qs[6]=f2bf(qb.z); qs[7]=f2bf(qb.w);
      *(short8*)&sm[QQ_OFF + lr*PITCH + j8] = qs;
    }
    __syncthreads();
    #pragma unroll
    for (int kk = 0; kk < 2; ++kk) {
      const bf16x8 a = *(const bf16x8*)&sm[CM_OFF + (cw + ln15)*PITCH + kk*32 + g*8];
      #pragma unroll
      for (int n = 0; n < 2; ++n) {
        const bf16x8 bq = *(const bf16x8*)&sm[QQ_OFF + (qw + n*16 + ln15)*PITCH + kk*32 + g*8];
        acc[n] = __builtin_amdgcn_mfma_f32_16x16x32_bf16(a, bq, acc[n], 0, 0, 0);
      }
    }
  }

  // s_c / s_q: reduce over the 8 stager lanes of each row
  scp += __shfl_xor(scp, 1, 8); scp += __shfl_xor(scp, 2, 8); scp += __shfl_xor(scp, 4, 8);
  sqp += __shfl_xor(sqp, 1, 8); sqp += __shfl_xor(sqp, 2, 8); sqp += __shfl_xor(sqp, 4, 8);
  if ((t & 7) == 0) { smf[SCS_F + lr] = scp; smf[SQS_F + lr] = sqp; }
  __syncthreads();

  // ---------- wave-partial softmax over this wave's 32 q (R7-verified pattern) ----------
  float ev0[4], ev1[4], pmr[4];
  #pragma unroll
  for (int reg = 0; reg < 4; ++reg) {
    float sv0 = acc[0][reg] + smf[SQS_F + qw + ln15];
    float sv1 = acc[1][reg] + smf[SQS_F + qw + 16 + ln15];
    float pm = fmaxf(sv0, sv1);
    pm = fmaxf(pm, __shfl_xor(pm, 1, 16));
    pm = fmaxf(pm, __shfl_xor(pm, 2, 16));
    pm = fmaxf(pm, __shfl_xor(pm, 4, 16));
    pm = fmaxf(pm, __shfl_xor(pm, 8, 16));
    const float e0 = __expf(sv0 - pm), e1 = __expf(sv1 - pm);
    float pe = e0 + e1;
    pe += __shfl_xor(pe, 1, 16); pe += __shfl_xor(pe, 2, 16);
    pe += __shfl_xor(pe, 4, 16); pe += __shfl_xor(pe, 8, 16);
    ev0[reg] = e0; ev1[reg] = e1; pmr[reg] = pm;
    if (ln15 == 0) { smf[PML_F + qh*64 + cw + g*4 + reg] = pm;
                     smf[PEL_F + qh*64 + cw + g*4 + reg] = pe; }
  }
  __syncthreads();   // partials visible

  // ---------- combine the two q-halves; write normalized P (s_c cancels in softmax) ----------
  #pragma unroll
  for (int reg = 0; reg < 4; ++reg) {
    const int rloc = cw + g*4 + reg;
    const float m0 = smf[PML_F + rloc], m1 = smf[PML_F + 64 + rloc];
    const float s0 = smf[PEL_F + rloc], s1 = smf[PEL_F + 64 + rloc];
    const float M  = fmaxf(m0, m1);
    const float S  = s0*__expf(m0 - M) + s1*__expf(m1 - M);
    const float f  = __expf(pmr[reg] - M) / S;
    if (qh == 0 && ln15 == 0) m_ws[b*NC + c0 + rloc] = M + smf[SCS_F + rloc];
    sm[P_OFF + rloc*PITCH + qw + ln15]      = f2bf(ev0[reg] * f);
    sm[P_OFF + rloc*PITCH + qw + 16 + ln15] = f2bf(ev1[reg] * f);
  }
  __syncthreads();   // P complete before fragment loads

  bf16x8 pa[2];
  pa[0] = *(const bf16x8*)&sm[P_OFF + (cw + ln15)*PITCH + g*8];
  pa[1] = *(const bf16x8*)&sm[P_OFF + (cw + ln15)*PITCH + 32 + g*8];

  // phase-B stager: thread stages q-row lr (col) x 8 d (rows) of qT
  // streaming mapping: 16 lanes per 256 B row segment
  const int sr = t >> 4, sc = (t & 15) * 4;

  // ---------- Phase B: aq = P @ query (K=64), fused epilogue parts 0,1,2 ----------
  for (int dc = 0; dc < 8; ++dc) {
    const int d0 = dc * 64;
    __syncthreads();   // prior chunk's qT MFMA reads + aqf store reads done
    {
      const float* qrow = qry + ((size_t)(b*NQ + lr))*ND + d0 + j8;
      const float4 a0 = *(const float4*)(qrow);
      const float4 a1 = *(const float4*)(qrow + 4);
      const float e[8] = {a0.x,a0.y,a0.z,a0.w,a1.x,a1.y,a1.z,a1.w};
      #pragma unroll
      for (int v = 0; v < 8; ++v) {
        const int dd = j8 + v;
        sm[CM_OFF + dd*PITCH + (lr ^ qswz(dd))] = f2bf(e[v]);
      }
    }
    __syncthreads();
    f32x4 acc2[2] = {};
    #pragma unroll
    for (int kk = 0; kk < 2; ++kk)
      #pragma unroll
      for (int n = 0; n < 2; ++n) {
        const int dd = qw + n*16 + ln15;
        const bf16x8 bq = *(const bf16x8*)&sm[CM_OFF + dd*PITCH + ((kk*32 + g*8) ^ qswz(dd))];
        acc2[n] = __builtin_amdgcn_mfma_f32_16x16x32_bf16(pa[kk], bq, acc2[n], 0, 0, 0);
      }
    #pragma unroll
    for (int n = 0; n < 2; ++n)
      #pragma unroll
      for (int reg = 0; reg < 4; ++reg)
        smf[AQF_F + (cw + g*4 + reg)*AQP + qw + n*16 + ln15] = acc2[n][reg];
    __syncthreads();   // aqf visible
    #pragma unroll
    for (int k4 = 0; k4 < 2; ++k4) {
      const int r = k4*32 + sr;
      const float4 aq4 = *(const float4*)&smf[AQF_F + r*AQP + sc];
      const float4 cv  = *(const float4*)(ctx + ((size_t)(b*NC + c0 + r))*ND + d0 + sc);
      float* gp = G + ((size_t)(b*NC + c0 + r))*2048 + d0 + sc;
      *(float4*)(gp)        = cv;                                           // part 0
      *(float4*)(gp + 512)  = aq4;                                          // part 1
      *(float4*)(gp + 1024) = make_float4(cv.x*aq4.x, cv.y*aq4.y,
                                          cv.z*aq4.z, cv.w*aq4.w);          // part 2
    }
  }
}

// ============ k2: b = softmax_c(m); attended_context (verbatim R2, proven) ============
__global__ __launch_bounds__(256) void k2_partial(
    const float* __restrict__ ctx, const float* __restrict__ m_ws, float* __restrict__ pc)
{
  const int t  = threadIdx.x;
  const int b  = blockIdx.x >> 4;
  const int ch = blockIdx.x & 15;
  __shared__ float r8[8];
  __shared__ float wts[32];

  const float v0 = m_ws[b*NC + t];
  const float v1 = m_ws[b*NC + 256 + t];
  float mx = fmaxf(v0, v1);
  #pragma unroll
  for (int o = 32; o; o >>= 1) mx = fmaxf(mx, __shfl_xor(mx, o, 64));
  if ((t & 63) == 0) r8[t >> 6] = mx;
  __syncthreads();
  mx = fmaxf(fmaxf(r8[0], r8[1]), fmaxf(r8[2], r8[3]));
  float e = __expf(v0 - mx) + __expf(v1 - mx);
  #pragma unroll
  for (int o = 32; o; o >>= 1) e += __shfl_xor(e, o, 64);
  if ((t & 63) == 0) r8[4 + (t >> 6)] = e;
  __syncthreads();
  const float denom = r8[4] + r8[5] + r8[6] + r8[7];
  if (t < 32) wts[t] = __expf(m_ws[b*NC + ch*32 + t] - mx) / denom;
  __syncthreads();

  float s0 = 0.f, s1 = 0.f;
  const float* base = ctx + ((size_t)(b*NC + ch*32))*ND;
  for (int c = 0; c < 32; ++c) {
    const float w = wts[c];
    s0 += w * base[(size_t)c*ND + t];
    s1 += w * base[(size_t)c*ND + t + 256];
  }
  pc[((size_t)(b*16 + ch))*ND + t]       = s0;
  pc[((size_t)(b*16 + ch))*ND + t + 256] = s1;
}

__global__ __launch_bounds__(512) void k2_reduce(
    const float* __restrict__ pc, float* __restrict__ ac)
{
  const int b = blockIdx.x;
  const int d = threadIdx.x;
  float s = 0.f;
  #pragma unroll
  for (int ch = 0; ch < 16; ++ch) s += pc[((size_t)(b*16 + ch))*ND + d];
  ac[b*ND + d] = s;
}

// ============ k3: G part 3 = ctx * attended_context (verbatim R2, proven) ============
__global__ __launch_bounds__(256) void k3_part3(
    const float* __restrict__ ctx, const float* __restrict__ ac, float* __restrict__ G)
{
  const size_t e = ((size_t)blockIdx.x*256 + threadIdx.x) * 8;
  const int b = (int)(e >> 18);
  const int r = (int)(e & 262143);
  const int c = r >> 9;
  const int d = r & 511;
  const float4 x0 = *(const float4*)(ctx + e);
  const float4 x1 = *(const float4*)(ctx + e + 4);
  const float4 a0 = *(const float4*)(ac + b*ND + d);
  const float4 a1 = *(const float4*)(ac + b*ND + d + 4);
  float* gp = G + ((size_t)(b*NC + c))*2048 + 1536 + d;
  *(float4*)(gp)     = make_float4(x0.x*a0.x, x0.y*a0.y, x0.z*a0.z, x0.w*a0.w);
  *(float4*)(gp + 4) = make_float4(x1.x*a1.x, x1.y*a1.y, x1.z*a1.z, x1.w*a1.w);
}

extern "C" void kernel_launch(void* const* d_in, const int* in_sizes, int n_in,
                              void* d_out, int out_size, void* d_ws, size_t ws_size,
                              hipStream_t stream)
{
  const float* ctx = (const float*)d_in[0];
  const float* qry = (const float*)d_in[1];
  const float* W   = (const float*)d_in[2];
  float* G = (float*)d_out;

  float* m_ws = (float*)d_ws;            // [32][512]
  float* pc   = m_ws + NB*NC;            // [32][16][512]
  float* ac   = pc + (size_t)NB*16*ND;   // [32][512]

  k1_main   <<<dim3(NB*8),  dim3(512), 0, stream>>>(ctx, qry, W, G, m_ws);
  k2_partial<<<dim3(NB*16), dim3(256), 0, stream>>>(ctx, m_ws, pc);
  k2_reduce <<<dim3(NB),    dim3(512), 0, stream>>>(pc, ac);
  k3_part3  <<<dim3((NB*NC*ND)/(256*8)), dim3(256), 0, stream>>>(ctx, ac, G);
}